// Round 4
// baseline (448.511 us; speedup 1.0000x reference)
//
#include <hip/hip_runtime.h>
#include <math.h>

// SSNN: y[n] = tanh(C x[n+1] + D u[n]),  x[n+1] = A x[n] + B u[n], x0 = 0.
// Truncate impulse response at W=16:  y[n] = tanh( sum_{k<16} G_k u[n-k] ),
// G_k = C A^k B (G_0 += D), built meet-in-the-middle:
//   P_i = C(2A)^i (i=0..3),  QT_j = ((2A)^j B)^T (j=0,4,8,12),  G_{i+j}=2^-(i+j) P_i QT_j^T
// One persistent chain kernel (5 stages, device atomic grid barrier) + conv-GEMM.
// All tile loops: 4-deep LDS pipeline, counted vmcnt + raw s_barrier (1/iter),
// XOR chunk swizzle (linear gload_lds dest + swizzled global src + swizzled read).

typedef _Float16 f16;
typedef _Float16 f16x8 __attribute__((ext_vector_type(8)));
typedef float f32x4 __attribute__((ext_vector_type(4)));

#define N_TOT   16384
#define ULEN    256
#define XLEN    1024
#define W       16
#define KTOT    (W*ULEN)       /* 4096 */
#define UH_ROWS (W + N_TOT)    /* 16400 */

// ---- workspace layout (bytes) ----
#define SZ_UH   ((unsigned long long)UH_ROWS*ULEN*2)   /* 8,396,800 */
#define SZ_SQ   ((unsigned long long)XLEN*XLEN*2)      /* 2 MiB */
#define SZ_RQ   ((unsigned long long)256*XLEN*2)       /* 512 KiB */
#define OFF_UH   0ull
#define OFF_AS   (OFF_UH + SZ_UH)            /* As, T1, A2, T2, A4, T4, A8 */
#define OFF_CC   (OFF_AS + 7*SZ_SQ)          /* Cc, P1, P2, P3 */
#define OFF_BT   (OFF_CC + 4*SZ_RQ)          /* BhT, QT4, QT8, QT12 */
#define OFF_GC   (OFF_BT + 4*SZ_RQ)          /* 256 x 4096 f16 */
#define OFF_BAR  (OFF_GC + SZ_SQ)

#define PTRS(ws) \
    f16* As  = (f16*)((ws) + OFF_AS); \
    f16* T1  = (f16*)((ws) + OFF_AS + 1*SZ_SQ); \
    f16* A2  = (f16*)((ws) + OFF_AS + 2*SZ_SQ); \
    f16* T2  = (f16*)((ws) + OFF_AS + 3*SZ_SQ); \
    f16* A4  = (f16*)((ws) + OFF_AS + 4*SZ_SQ); \
    f16* T4  = (f16*)((ws) + OFF_AS + 5*SZ_SQ); \
    f16* A8  = (f16*)((ws) + OFF_AS + 6*SZ_SQ); \
    f16* Cc  = (f16*)((ws) + OFF_CC); \
    f16* P1  = (f16*)((ws) + OFF_CC + 1*SZ_RQ); \
    f16* P2  = (f16*)((ws) + OFF_CC + 2*SZ_RQ); \
    f16* P3  = (f16*)((ws) + OFF_CC + 3*SZ_RQ); \
    f16* BhT = (f16*)((ws) + OFF_BT); \
    f16* QT4 = (f16*)((ws) + OFF_BT + 1*SZ_RQ); \
    f16* QT8 = (f16*)((ws) + OFF_BT + 2*SZ_RQ); \
    f16* QT12= (f16*)((ws) + OFF_BT + 3*SZ_RQ); \
    f16* Gc  = (f16*)((ws) + OFF_GC);

// async global->LDS, 16B/lane; LDS base wave-uniform (lane scatters +l*16B)
__device__ __forceinline__ void gload16(const void* g, void* l) {
    __builtin_amdgcn_global_load_lds(
        (const __attribute__((address_space(1))) void*)g,
        (__attribute__((address_space(3))) void*)l, 16, 0, 0);
}

__device__ __forceinline__ void waitv(int n) {
    switch (n) {
        case 0:  asm volatile("s_waitcnt vmcnt(0)" ::: "memory"); break;
        case 1:  asm volatile("s_waitcnt vmcnt(1)" ::: "memory"); break;
        case 2:  asm volatile("s_waitcnt vmcnt(2)" ::: "memory"); break;
        default: asm volatile("s_waitcnt vmcnt(4)" ::: "memory"); break;
    }
}

// device-scope sense-reversing grid barrier (all gridDim.x blocks co-resident)
__device__ __forceinline__ void grid_sync(unsigned* bar) {
    __syncthreads();
    if (threadIdx.x == 0) {
        __threadfence();   // release my stage's global writes (L2 writeback)
        unsigned gen = __hip_atomic_load(&bar[1], __ATOMIC_ACQUIRE, __HIP_MEMORY_SCOPE_AGENT);
        unsigned arr = __hip_atomic_fetch_add(&bar[0], 1u, __ATOMIC_ACQ_REL, __HIP_MEMORY_SCOPE_AGENT);
        if (arr == gridDim.x - 1) {
            __hip_atomic_store(&bar[0], 0u, __ATOMIC_RELAXED, __HIP_MEMORY_SCOPE_AGENT);
            __hip_atomic_fetch_add(&bar[1], 1u, __ATOMIC_ACQ_REL, __HIP_MEMORY_SCOPE_AGENT);
        } else {
            while (__hip_atomic_load(&bar[1], __ATOMIC_ACQUIRE, __HIP_MEMORY_SCOPE_AGENT) == gen)
                __builtin_amdgcn_s_sleep(8);
        }
    }
    __syncthreads();
}

// ---------------- prep: casts / transposes / zero-pad (8 f16 per thread) -------
__global__ void prep_kernel(const float* __restrict__ u, const float* __restrict__ A,
                            const float* __restrict__ B, const float* __restrict__ C,
                            char* __restrict__ ws) {
    PTRS(ws)
    f16* Uh = (f16*)(ws + OFF_UH);
    if (blockIdx.x == 0 && threadIdx.x == 0) {
        unsigned* bar = (unsigned*)(ws + OFF_BAR);
        bar[0] = 0; bar[1] = 0;
    }
    const int NU = UH_ROWS*ULEN/8;   // 524800
    const int NA = XLEN*XLEN/8;      // 131072
    const int NC = 256*XLEN/8;       // 32768
    const int NB = XLEN*ULEN/8;      // 32768
    int idx = blockIdx.x*256 + threadIdx.x;
    if (idx < NU) {                              // Uh[W+n][j] = u[n][j]; rows<W = 0
        const int r = idx >> 5, c8 = (idx & 31) * 8;
        f16x8 v = {};
        if (r >= W) {
            const float4 a = *(const float4*)&u[(long long)(r - W)*ULEN + c8];
            const float4 b = *(const float4*)&u[(long long)(r - W)*ULEN + c8 + 4];
            v[0]=(f16)a.x; v[1]=(f16)a.y; v[2]=(f16)a.z; v[3]=(f16)a.w;
            v[4]=(f16)b.x; v[5]=(f16)b.y; v[6]=(f16)b.z; v[7]=(f16)b.w;
        }
        *(f16x8*)&Uh[(long long)r*ULEN + c8] = v;
    } else if ((idx -= NU) < NA) {               // As = 2A (fp16-range-safe powers)
        const float4 a = *(const float4*)&A[(long long)idx*8];
        const float4 b = *(const float4*)&A[(long long)idx*8 + 4];
        f16x8 v;
        v[0]=(f16)(2.0f*a.x); v[1]=(f16)(2.0f*a.y); v[2]=(f16)(2.0f*a.z); v[3]=(f16)(2.0f*a.w);
        v[4]=(f16)(2.0f*b.x); v[5]=(f16)(2.0f*b.y); v[6]=(f16)(2.0f*b.z); v[7]=(f16)(2.0f*b.w);
        *(f16x8*)&As[(long long)idx*8] = v;
    } else if ((idx -= NA) < NA) {               // T1[c][r] = 2A[r][c], scatter write
        const int r = idx >> 7, c8 = (idx & 127) * 8;
        const float4 a = *(const float4*)&A[(long long)r*XLEN + c8];
        const float4 b = *(const float4*)&A[(long long)r*XLEN + c8 + 4];
        T1[(long long)(c8+0)*XLEN + r] = (f16)(2.0f*a.x);
        T1[(long long)(c8+1)*XLEN + r] = (f16)(2.0f*a.y);
        T1[(long long)(c8+2)*XLEN + r] = (f16)(2.0f*a.z);
        T1[(long long)(c8+3)*XLEN + r] = (f16)(2.0f*a.w);
        T1[(long long)(c8+4)*XLEN + r] = (f16)(2.0f*b.x);
        T1[(long long)(c8+5)*XLEN + r] = (f16)(2.0f*b.y);
        T1[(long long)(c8+6)*XLEN + r] = (f16)(2.0f*b.z);
        T1[(long long)(c8+7)*XLEN + r] = (f16)(2.0f*b.w);
    } else if ((idx -= NA) < NC) {               // Cc = C cast
        const float4 a = *(const float4*)&C[(long long)idx*8];
        const float4 b = *(const float4*)&C[(long long)idx*8 + 4];
        f16x8 v;
        v[0]=(f16)a.x; v[1]=(f16)a.y; v[2]=(f16)a.z; v[3]=(f16)a.w;
        v[4]=(f16)b.x; v[5]=(f16)b.y; v[6]=(f16)b.z; v[7]=(f16)b.w;
        *(f16x8*)&Cc[(long long)idx*8] = v;
    } else if ((idx -= NC) < NB) {               // BhT[j][x] = B[x][j], scatter write
        const int r = idx >> 5, c8 = (idx & 31) * 8;   // B row r (x), cols c8 (j)
        const float4 a = *(const float4*)&B[(long long)r*ULEN + c8];
        const float4 b = *(const float4*)&B[(long long)r*ULEN + c8 + 4];
        BhT[(long long)(c8+0)*XLEN + r] = (f16)a.x;
        BhT[(long long)(c8+1)*XLEN + r] = (f16)a.y;
        BhT[(long long)(c8+2)*XLEN + r] = (f16)a.z;
        BhT[(long long)(c8+3)*XLEN + r] = (f16)a.w;
        BhT[(long long)(c8+4)*XLEN + r] = (f16)b.x;
        BhT[(long long)(c8+5)*XLEN + r] = (f16)b.y;
        BhT[(long long)(c8+6)*XLEN + r] = (f16)b.z;
        BhT[(long long)(c8+7)*XLEN + r] = (f16)b.w;
    }
}

// ------------- chain tile: Out(128x128 at o0,n0) = Aop @ BT^T, K=1024 -----------
// kb<0: f16 out (ld 1024). kb>=0: G-epilogue -> Gc[o][kb*256+c], 2^-kb, +D at kb=0.
// 4-buf pipeline, issue-3-ahead, counted vmcnt, one raw barrier per iter.
__device__ __noinline__ void chain_tile(
    const f16* __restrict__ Aop, const f16* __restrict__ BT,
    f16* __restrict__ outF, int kb, const float* __restrict__ Dmat,
    f16* __restrict__ Gc, int o0, int n0, f16* lsA, f16* lsB)
{
    const int tid = threadIdx.x, l = tid & 63, w = tid >> 6;   // 8 waves
    const int wo = (w >> 2) * 64, wn = (w & 3) * 32;           // 64x32 quadrant
    const int lr = l & 15, lh = l >> 4;
    const int srow = tid >> 2;                                 // staging row 0..127
    const int q = (tid & 3) ^ ((srow >> 1) & 3);               // inv-swizzled chunk
    f32x4 acc[4][2] = {};

#define CSTG(buf, t) do { \
    gload16(Aop + (long long)(o0 + srow)*XLEN + (t)*32 + q*8, &lsA[(buf)*4096 + w*512]); \
    gload16(BT  + (long long)(n0 + srow)*XLEN + (t)*32 + q*8, &lsB[(buf)*4096 + w*512]); \
} while (0)

    CSTG(0, 0); CSTG(1, 1); CSTG(2, 2);
    for (int kt = 0; kt < 32; ++kt) {
        { int d = 31 - kt; if (d > 2) d = 2; waitv(2*d); }   // own stage-kt loads done
        __builtin_amdgcn_s_barrier();                        // all waves' rows landed
        __builtin_amdgcn_sched_barrier(0);
        const int cur = kt & 3, sw = (lr >> 1) & 3;
        f16x8 af[4], bf[2];
#pragma unroll
        for (int mt = 0; mt < 4; ++mt)
            af[mt] = *(const f16x8*)&lsA[cur*4096 + (wo + mt*16 + lr)*32 + ((lh ^ sw)*8)];
#pragma unroll
        for (int nt = 0; nt < 2; ++nt)
            bf[nt] = *(const f16x8*)&lsB[cur*4096 + (wn + nt*16 + lr)*32 + ((lh ^ sw)*8)];
        if (kt + 3 < 32) CSTG((kt + 3) & 3, kt + 3);         // after barrier: WAR-safe
#pragma unroll
        for (int mt = 0; mt < 4; ++mt)
#pragma unroll
            for (int nt = 0; nt < 2; ++nt)
                acc[mt][nt] = __builtin_amdgcn_mfma_f32_16x16x32_f16(
                    af[mt], bf[nt], acc[mt][nt], 0, 0, 0);
        __builtin_amdgcn_sched_barrier(0);
    }
#undef CSTG

#pragma unroll
    for (int mt = 0; mt < 4; ++mt)
#pragma unroll
        for (int nt = 0; nt < 2; ++nt)
#pragma unroll
            for (int rg = 0; rg < 4; ++rg) {
                const int r = o0 + wo + mt*16 + lh*4 + rg;   // C/D: row=(l>>4)*4+reg
                const int c = n0 + wn + nt*16 + lr;          //      col=l&15
                float v = acc[mt][nt][rg];
                if (kb < 0) {
                    outF[(long long)r*XLEN + c] = (f16)v;
                } else {
                    v = ldexpf(v, -kb);                      // undo (2A)^k scaling
                    if (kb == 0) v += Dmat[r*ULEN + c];
                    Gc[(long long)r*KTOT + kb*256 + c] = (f16)v;
                }
            }
}

// ---------- persistent chain: 5 stages, grid barrier between (grid=256) ---------
__global__ __launch_bounds__(512) void chain_kernel(char* __restrict__ ws,
                                                    const float* __restrict__ D) {
    __shared__ __align__(16) f16 lsA[4*4096];
    __shared__ __align__(16) f16 lsB[4*4096];
    PTRS(ws)
    unsigned* bar = (unsigned*)(ws + OFF_BAR);
    const int b = blockIdx.x;
    // S1: A2=(2A)^2, T2=A2^T, P1=C(2A)            [144 jobs]
    if (b < 64)       chain_tile(As, T1, A2, -1, nullptr, nullptr, (b>>3)*128, (b&7)*128, lsA, lsB);
    else if (b < 128) chain_tile(T1, As, T2, -1, nullptr, nullptr, ((b-64)>>3)*128, ((b-64)&7)*128, lsA, lsB);
    else if (b < 144) chain_tile(Cc, T1, P1, -1, nullptr, nullptr, ((b-128)>>3)*128, ((b-128)&7)*128, lsA, lsB);
    grid_sync(bar);
    // S2: A4, T4, P2=C A2, P3=P1 A2               [160 jobs]
    if (b < 64)       chain_tile(A2, T2, A4, -1, nullptr, nullptr, (b>>3)*128, (b&7)*128, lsA, lsB);
    else if (b < 128) chain_tile(T2, A2, T4, -1, nullptr, nullptr, ((b-64)>>3)*128, ((b-64)&7)*128, lsA, lsB);
    else if (b < 144) chain_tile(Cc, T2, P2, -1, nullptr, nullptr, ((b-128)>>3)*128, ((b-128)&7)*128, lsA, lsB);
    else if (b < 160) chain_tile(P1, T2, P3, -1, nullptr, nullptr, ((b-144)>>3)*128, ((b-144)&7)*128, lsA, lsB);
    grid_sync(bar);
    // S3: A8, QT4=(A4 B)^T                        [80 jobs]
    if (b < 64)       chain_tile(A4, T4, A8, -1, nullptr, nullptr, (b>>3)*128, (b&7)*128, lsA, lsB);
    else if (b < 80)  chain_tile(BhT, A4, QT4, -1, nullptr, nullptr, ((b-64)>>3)*128, ((b-64)&7)*128, lsA, lsB);
    grid_sync(bar);
    // S4: QT8=(A8 B)^T, QT12=QT4 A8^T             [32 jobs]
    if (b < 16)       chain_tile(BhT, A8, QT8, -1, nullptr, nullptr, (b>>3)*128, (b&7)*128, lsA, lsB);
    else if (b < 32)  chain_tile(QT4, A8, QT12, -1, nullptr, nullptr, ((b-16)>>3)*128, ((b-16)&7)*128, lsA, lsB);
    grid_sync(bar);
    // S5: G_k = 2^-k P_i QT_j^T (k=i+4j)          [64 jobs]
    if (b < 64) {
        const int k = b >> 2, quad = b & 3, i = k & 3, jj = k >> 2;
        const f16* Pl[4] = {Cc, P1, P2, P3};
        const f16* Ql[4] = {BhT, QT4, QT8, QT12};
        chain_tile(Pl[i], Ql[jj], nullptr, k, D, Gc, (quad>>1)*128, (quad&1)*128, lsA, lsB);
    }
}

// ---------------- conv: out[o][n] = tanh( sum G[o][k*256+j] Uh[W+n-k][j] ) ------
// 128(M) x 64(N) tile; Uh window (79x256, row-XOR swizzle) staged once;
// G streamed via 4-buf pipeline (1 gload/thread/stage).
__global__ __launch_bounds__(512) void conv_kernel(const f16* __restrict__ Gc,
                                                   const f16* __restrict__ Uh,
                                                   float* __restrict__ out) {
    __shared__ __align__(16) f16 lsA[4*4096];
    __shared__ __align__(16) f16 lsW[79*256];
    const int tid = threadIdx.x, l = tid & 63, w = tid >> 6;
    const int n0 = blockIdx.x * 64, o0 = blockIdx.y * 128;
    const int wo = (w >> 1) * 32, wn = (w & 1) * 32;           // 32x32 per wave
    const int lr = l & 15, lh = l >> 4;
    const int srow = tid >> 2, q = (tid & 3) ^ ((srow >> 1) & 3);
    // stage Uh window rows [W+n0-15, W+n0+64), chunk c at phys c^(r&31)
    for (int i = tid; i < 79*32; i += 512) {
        const int r = i >> 5, c = i & 31;
        f16x8 v = *(const f16x8*)&Uh[(long long)(W + n0 - 15 + r)*ULEN + c*8];
        *(f16x8*)&lsW[r*256 + ((c ^ (r & 31)) * 8)] = v;
    }
    __syncthreads();
#define ASTG(buf, t) gload16(Gc + (long long)(o0 + srow)*KTOT + (t)*32 + q*8, \
                             &lsA[(buf)*4096 + w*512])
    ASTG(0, 0); ASTG(1, 1); ASTG(2, 2);
    f32x4 acc[2][2] = {};
    for (int kt = 0; kt < 128; ++kt) {
        { int d = 127 - kt; if (d > 2) d = 2; waitv(d); }
        __builtin_amdgcn_s_barrier();
        __builtin_amdgcn_sched_barrier(0);
        const int cur = kt & 3, sw = (lr >> 1) & 3;
        const int k_ = kt >> 3, qb = (kt & 7) * 4;
        f16x8 af[2], bf[2];
#pragma unroll
        for (int mt = 0; mt < 2; ++mt)
            af[mt] = *(const f16x8*)&lsA[cur*4096 + (wo + mt*16 + lr)*32 + ((lh ^ sw)*8)];
#pragma unroll
        for (int nt = 0; nt < 2; ++nt) {
            const int rl = 15 - k_ + wn + nt*16 + lr;          // window-local row
            bf[nt] = *(const f16x8*)&lsW[rl*256 + (((qb + lh) ^ (rl & 31)) * 8)];
        }
        if (kt + 3 < 128) ASTG((kt + 3) & 3, kt + 3);
#pragma unroll
        for (int mt = 0; mt < 2; ++mt)
#pragma unroll
            for (int nt = 0; nt < 2; ++nt)
                acc[mt][nt] = __builtin_amdgcn_mfma_f32_16x16x32_f16(
                    af[mt], bf[nt], acc[mt][nt], 0, 0, 0);
        __builtin_amdgcn_sched_barrier(0);
    }
#undef ASTG
#pragma unroll
    for (int mt = 0; mt < 2; ++mt)
#pragma unroll
        for (int nt = 0; nt < 2; ++nt)
#pragma unroll
            for (int rg = 0; rg < 4; ++rg) {
                const int r = o0 + wo + mt*16 + lh*4 + rg;
                const int c = n0 + wn + nt*16 + lr;
                const float v = acc[mt][nt][rg];
                const float t = __expf(-2.0f * fabsf(v));
                out[(long long)r*N_TOT + c] = copysignf((1.0f - t) / (1.0f + t), v);
            }
}

extern "C" void kernel_launch(void* const* d_in, const int* in_sizes, int n_in,
                              void* d_out, int out_size, void* d_ws, size_t ws_size,
                              hipStream_t stream) {
    const float* u = (const float*)d_in[0];
    const float* A = (const float*)d_in[1];
    const float* B = (const float*)d_in[2];
    const float* C = (const float*)d_in[3];
    const float* D = (const float*)d_in[4];
    char* ws = (char*)d_ws;
    f16* Uh = (f16*)(ws + OFF_UH);
    f16* Gc = (f16*)(ws + OFF_GC);
    float* out = (float*)d_out;

    prep_kernel<<<3330, 256, 0, stream>>>(u, A, B, C, ws);
    chain_kernel<<<256, 512, 0, stream>>>(ws, D);
    conv_kernel<<<dim3(N_TOT/64, 2), 512, 0, stream>>>(Gc, Uh, out);
}

// Round 8
// 261.494 us; speedup vs baseline: 1.7152x; 1.7152x over previous
//
#include <hip/hip_runtime.h>
#include <math.h>

// SSNN: y[n] = tanh(C x[n+1] + D u[n]),  x[n+1] = A x[n] + B u[n], x0 = 0.
// Truncate impulse response at W=16:  y[n] = tanh( sum_{k<16} G_k u[n-k] ),
// G_k = C A^k B (G_0 += D), built meet-in-the-middle:
//   P_i = C(2A)^i (i=0..3), QT_j = ((2A)^j B)^T (j=0,4,8,12), G_{i+4j}=2^-k P_i QT_j^T
//
// COMPILER ENVELOPE (R2..R7 evidence, clang-22 roc-7.2): TUs with ANY inline asm
// crash the frontend 3/4 times (R5,R6,R7; R4 lucky). Asm-free TUs: 2/2 OK.
// => this TU is 100% asm-free: only global_load_lds/mfma builtins + __syncthreads.
// Latency hiding comes from TLP (small tiles, many blocks/CU), not counted vmcnt.

typedef _Float16 f16;
typedef _Float16 f16x8 __attribute__((ext_vector_type(8)));
typedef float f32x4 __attribute__((ext_vector_type(4)));

#define N_TOT   16384
#define ULEN    256
#define XLEN    1024
#define W       16
#define KTOT    (W*ULEN)       /* 4096 */
#define UH_ROWS (W + N_TOT)    /* 16400 */
#define RQE     (256*XLEN)     /* elements in one 256x1024 panel */

// ---- workspace layout (bytes) ----
#define SZ_UH   ((unsigned long long)UH_ROWS*ULEN*2)
#define SZ_SQ   ((unsigned long long)XLEN*XLEN*2)      /* 2 MiB */
#define SZ_RQ   ((unsigned long long)RQE*2)            /* 512 KiB */
#define OFF_UH   0ull
#define OFF_AS   (OFF_UH + SZ_UH)            /* As, T1, A2, T2, A4, T4, A8 */
#define OFF_CC   (OFF_AS + 7*SZ_SQ)          /* Cc, P1, P2, P3 (contiguous) */
#define OFF_BT   (OFF_CC + 4*SZ_RQ)          /* BhT, QT4, QT8, QT12 (contiguous) */
#define OFF_GC   (OFF_BT + 4*SZ_RQ)          /* 256 x 4096 f16 */

#define PTRS(ws) \
    f16* As  = (f16*)((ws) + OFF_AS); \
    f16* T1  = (f16*)((ws) + OFF_AS + 1*SZ_SQ); \
    f16* A2  = (f16*)((ws) + OFF_AS + 2*SZ_SQ); \
    f16* T2  = (f16*)((ws) + OFF_AS + 3*SZ_SQ); \
    f16* A4  = (f16*)((ws) + OFF_AS + 4*SZ_SQ); \
    f16* T4  = (f16*)((ws) + OFF_AS + 5*SZ_SQ); \
    f16* A8  = (f16*)((ws) + OFF_AS + 6*SZ_SQ); \
    f16* Cc  = (f16*)((ws) + OFF_CC); \
    f16* P1  = (f16*)((ws) + OFF_CC + 1*SZ_RQ); \
    f16* P2  = (f16*)((ws) + OFF_CC + 2*SZ_RQ); \
    f16* P3  = (f16*)((ws) + OFF_CC + 3*SZ_RQ); \
    f16* BhT = (f16*)((ws) + OFF_BT); \
    f16* QT4 = (f16*)((ws) + OFF_BT + 1*SZ_RQ); \
    f16* QT8 = (f16*)((ws) + OFF_BT + 2*SZ_RQ); \
    f16* QT12= (f16*)((ws) + OFF_BT + 3*SZ_RQ); \
    f16* Gc  = (f16*)((ws) + OFF_GC);

// async global->LDS, 16B/lane; LDS base wave-uniform (lane scatters +l*16B)
__device__ __forceinline__ void gload16(const void* g, void* l) {
    __builtin_amdgcn_global_load_lds(
        (const __attribute__((address_space(1))) void*)g,
        (__attribute__((address_space(3))) void*)l, 16, 0, 0);
}

// ---------------- prep: casts / transposes / zero-pad (8 f16 per thread) -------
__global__ void prep_kernel(const float* __restrict__ u, const float* __restrict__ A,
                            const float* __restrict__ B, const float* __restrict__ C,
                            char* __restrict__ ws) {
    PTRS(ws)
    f16* Uh = (f16*)(ws + OFF_UH);
    const int NU = UH_ROWS*ULEN/8;   // 524800
    const int NA = XLEN*XLEN/8;      // 131072
    const int NC = 256*XLEN/8;       // 32768
    const int NB = XLEN*ULEN/8;      // 32768
    int idx = blockIdx.x*256 + threadIdx.x;
    if (idx < NU) {                              // Uh[W+n][j] = u[n][j]; rows<W = 0
        const int r = idx >> 5, c8 = (idx & 31) * 8;
        f16x8 v = {};
        if (r >= W) {
            const float4 a = *(const float4*)&u[(long long)(r - W)*ULEN + c8];
            const float4 b = *(const float4*)&u[(long long)(r - W)*ULEN + c8 + 4];
            v[0]=(f16)a.x; v[1]=(f16)a.y; v[2]=(f16)a.z; v[3]=(f16)a.w;
            v[4]=(f16)b.x; v[5]=(f16)b.y; v[6]=(f16)b.z; v[7]=(f16)b.w;
        }
        *(f16x8*)&Uh[(long long)r*ULEN + c8] = v;
    } else if ((idx -= NU) < NA) {               // As = 2A (fp16-range-safe powers)
        const float4 a = *(const float4*)&A[(long long)idx*8];
        const float4 b = *(const float4*)&A[(long long)idx*8 + 4];
        f16x8 v;
        v[0]=(f16)(2.0f*a.x); v[1]=(f16)(2.0f*a.y); v[2]=(f16)(2.0f*a.z); v[3]=(f16)(2.0f*a.w);
        v[4]=(f16)(2.0f*b.x); v[5]=(f16)(2.0f*b.y); v[6]=(f16)(2.0f*b.z); v[7]=(f16)(2.0f*b.w);
        *(f16x8*)&As[(long long)idx*8] = v;
    } else if ((idx -= NA) < NA) {               // T1[c][r] = 2A[r][c], scatter write
        const int r = idx >> 7, c8 = (idx & 127) * 8;
        const float4 a = *(const float4*)&A[(long long)r*XLEN + c8];
        const float4 b = *(const float4*)&A[(long long)r*XLEN + c8 + 4];
        T1[(long long)(c8+0)*XLEN + r] = (f16)(2.0f*a.x);
        T1[(long long)(c8+1)*XLEN + r] = (f16)(2.0f*a.y);
        T1[(long long)(c8+2)*XLEN + r] = (f16)(2.0f*a.z);
        T1[(long long)(c8+3)*XLEN + r] = (f16)(2.0f*a.w);
        T1[(long long)(c8+4)*XLEN + r] = (f16)(2.0f*b.x);
        T1[(long long)(c8+5)*XLEN + r] = (f16)(2.0f*b.y);
        T1[(long long)(c8+6)*XLEN + r] = (f16)(2.0f*b.z);
        T1[(long long)(c8+7)*XLEN + r] = (f16)(2.0f*b.w);
    } else if ((idx -= NA) < NC) {               // Cc = C cast
        const float4 a = *(const float4*)&C[(long long)idx*8];
        const float4 b = *(const float4*)&C[(long long)idx*8 + 4];
        f16x8 v;
        v[0]=(f16)a.x; v[1]=(f16)a.y; v[2]=(f16)a.z; v[3]=(f16)a.w;
        v[4]=(f16)b.x; v[5]=(f16)b.y; v[6]=(f16)b.z; v[7]=(f16)b.w;
        *(f16x8*)&Cc[(long long)idx*8] = v;
    } else if ((idx -= NC) < NB) {               // BhT[j][x] = B[x][j], scatter write
        const int r = idx >> 5, c8 = (idx & 31) * 8;   // B row r (x), cols c8 (j)
        const float4 a = *(const float4*)&B[(long long)r*ULEN + c8];
        const float4 b = *(const float4*)&B[(long long)r*ULEN + c8 + 4];
        BhT[(long long)(c8+0)*XLEN + r] = (f16)a.x;
        BhT[(long long)(c8+1)*XLEN + r] = (f16)a.y;
        BhT[(long long)(c8+2)*XLEN + r] = (f16)a.z;
        BhT[(long long)(c8+3)*XLEN + r] = (f16)a.w;
        BhT[(long long)(c8+4)*XLEN + r] = (f16)b.x;
        BhT[(long long)(c8+5)*XLEN + r] = (f16)b.y;
        BhT[(long long)(c8+6)*XLEN + r] = (f16)b.z;
        BhT[(long long)(c8+7)*XLEN + r] = (f16)b.w;
    }
}

// ------- 64x64 chain tile (ASM-FREE): Out(64x64 at o0,n0) = Aop @ BT^T, K=1024 --
// 4 waves, 32x32 quadrant each (acc 2x2). 2-buffer LDS, one __syncthreads/iter.
// MODE 0: f16 out ld=1024. MODE 1: Gc[r][kb*256+c] = 2^-kb * v (+D at kb=0).
// Swizzle: LDS row r stores logical 16B-chunk p at phys p^((r>>1)&3) (proven 0-confl).
template<int MODE>
__device__ __forceinline__ void gemm_body64(
    const f16* __restrict__ Aop, const f16* __restrict__ BT,
    f16* __restrict__ outF, int kb, const float* __restrict__ Dmat,
    f16* __restrict__ Gc, int o0, int n0, f16* lsA, f16* lsB)
{
    const int tid = threadIdx.x, l = tid & 63, w = tid >> 6;   // 4 waves
    const int wo = (w >> 1) * 32, wn = (w & 1) * 32;           // 32x32 quadrant
    const int lr = l & 15, lh = l >> 4;
    const int srow = tid >> 2;                                 // staging row 0..63
    const int q = (tid & 3) ^ ((srow >> 1) & 3);               // inv-swizzled chunk
    f32x4 acc[2][2] = {};

#define CSTG(buf, t) do { \
    gload16(Aop + (long long)(o0 + srow)*XLEN + (t)*32 + q*8, &lsA[(buf)*2048 + w*512]); \
    gload16(BT  + (long long)(n0 + srow)*XLEN + (t)*32 + q*8, &lsB[(buf)*2048 + w*512]); \
} while (0)

    CSTG(0, 0);
    __syncthreads();                    // drains vmcnt: buf0 ready
    for (int kt = 0; kt < 32; ++kt) {
        const int cur = kt & 1;
        if (kt + 1 < 32) CSTG(cur ^ 1, kt + 1);    // prefetch overlaps compute
        const int sw = (lr >> 1) & 3;
        f16x8 af[2], bf[2];
#pragma unroll
        for (int mt = 0; mt < 2; ++mt)
            af[mt] = *(const f16x8*)&lsA[cur*2048 + (wo + mt*16 + lr)*32 + ((lh ^ sw)*8)];
#pragma unroll
        for (int nt = 0; nt < 2; ++nt)
            bf[nt] = *(const f16x8*)&lsB[cur*2048 + (wn + nt*16 + lr)*32 + ((lh ^ sw)*8)];
#pragma unroll
        for (int mt = 0; mt < 2; ++mt)
#pragma unroll
            for (int nt = 0; nt < 2; ++nt)
                acc[mt][nt] = __builtin_amdgcn_mfma_f32_16x16x32_f16(
                    af[mt], bf[nt], acc[mt][nt], 0, 0, 0);
        __syncthreads();                // prefetch landed; readers done with cur
    }
#undef CSTG

#pragma unroll
    for (int mt = 0; mt < 2; ++mt)
#pragma unroll
        for (int nt = 0; nt < 2; ++nt)
#pragma unroll
            for (int rg = 0; rg < 4; ++rg) {
                const int r = o0 + wo + mt*16 + lh*4 + rg;   // C/D: row=(l>>4)*4+reg
                const int c = n0 + wn + nt*16 + lr;          //      col=l&15
                float v = acc[mt][nt][rg];
                if (MODE == 0) {
                    outF[(long long)r*XLEN + c] = (f16)v;
                } else {
                    v = ldexpf(v, -kb);                      // undo (2A)^k scaling
                    if (kb == 0) v += Dmat[r*ULEN + c];
                    Gc[(long long)r*KTOT + kb*256 + c] = (f16)v;
                }
            }
}

// ---- stage GEMM: up to 4 operand segments by cumulative block counts ----------
// (direct gemm_body64 call per branch — R3's compile-proven pattern)
__global__ __launch_bounds__(256) void stage64_kernel(
    const f16* A0, const f16* B0, f16* O0, int c0,
    const f16* A1, const f16* B1, f16* O1, int c1,
    const f16* A2s, const f16* B2s, f16* O2s, int c2,
    const f16* A3s, const f16* B3s, f16* O3s)
{
    __shared__ __align__(16) f16 lsA[2*2048];
    __shared__ __align__(16) f16 lsB[2*2048];
    const int b = blockIdx.x;
    if (b < c0) {
        gemm_body64<0>(A0, B0, O0, -1, nullptr, nullptr,
                       (b>>4)*64, (b&15)*64, lsA, lsB);
    } else if (b < c1) {
        const int t = b - c0;
        gemm_body64<0>(A1, B1, O1, -1, nullptr, nullptr,
                       (t>>4)*64, (t&15)*64, lsA, lsB);
    } else if (b < c2) {
        const int t = b - c1;
        gemm_body64<0>(A2s, B2s, O2s, -1, nullptr, nullptr,
                       (t>>4)*64, (t&15)*64, lsA, lsB);
    } else {
        const int t = b - c2;
        gemm_body64<0>(A3s, B3s, O3s, -1, nullptr, nullptr,
                       (t>>4)*64, (t&15)*64, lsA, lsB);
    }
}

// ---- S5: G_k = 2^-k P_(k&3) @ QT_(k>>2)^T; panel pointers COMPUTED ------------
// grid = 16 k-values x 16 (4x4) 64x64 tiles = 256 blocks.
__global__ __launch_bounds__(256) void g64_kernel(
    const f16* __restrict__ Pbase, const f16* __restrict__ Qbase,
    f16* __restrict__ Gc, const float* __restrict__ D)
{
    __shared__ __align__(16) f16 lsA[2*2048];
    __shared__ __align__(16) f16 lsB[2*2048];
    const int b = blockIdx.x, k = b >> 4, t = b & 15;
    const f16* Ap = Pbase + (long long)(k & 3) * RQE;
    const f16* Bp = Qbase + (long long)(k >> 2) * RQE;
    gemm_body64<1>(Ap, Bp, nullptr, k, D, Gc, (t>>2)*64, (t&3)*64, lsA, lsB);
}

// ---------------- conv (ASM-FREE): out[o][n] = tanh( sum_k G_k u[n-k] ) ---------
// 64x64 tile, 256 thr (4 waves, 32x32 each), grid (256,4) = 1024 blocks ~3/CU.
// Uh window (79x256, row-XOR chunk swizzle) staged ONCE; G streamed 2-buf.
__global__ __launch_bounds__(256) void conv_kernel(const f16* __restrict__ Gc,
                                                   const f16* __restrict__ Uh,
                                                   float* __restrict__ out) {
    __shared__ __align__(16) f16 lsA[2*2048];
    __shared__ __align__(16) f16 lsW[79*256];
    const int tid = threadIdx.x, l = tid & 63, w = tid >> 6;
    const int n0 = blockIdx.x * 64, o0 = blockIdx.y * 64;
    const int wo = (w >> 1) * 32, wn = (w & 1) * 32;
    const int lr = l & 15, lh = l >> 4;
    const int srow = tid >> 2, q = (tid & 3) ^ ((srow >> 1) & 3);
    // stage Uh window rows [W+n0-15, W+n0+64), chunk c at phys c^(r&31)
    for (int i = tid; i < 79*32; i += 256) {
        const int r = i >> 5, c = i & 31;
        f16x8 v = *(const f16x8*)&Uh[(long long)(W + n0 - 15 + r)*ULEN + c*8];
        *(f16x8*)&lsW[r*256 + ((c ^ (r & 31)) * 8)] = v;
    }
#define ASTG(buf, t) gload16(Gc + (long long)(o0 + srow)*KTOT + (t)*32 + q*8, \
                             &lsA[(buf)*2048 + w*512])
    ASTG(0, 0);
    __syncthreads();                    // window + buf0 ready
    f32x4 acc[2][2] = {};
    for (int kt = 0; kt < 128; ++kt) {
        const int cur = kt & 1;
        if (kt + 1 < 128) ASTG(cur ^ 1, kt + 1);
        const int sw = (lr >> 1) & 3;
        const int k_ = kt >> 3, qb = (kt & 7) * 4;
        f16x8 af[2], bf[2];
#pragma unroll
        for (int mt = 0; mt < 2; ++mt)
            af[mt] = *(const f16x8*)&lsA[cur*2048 + (wo + mt*16 + lr)*32 + ((lh ^ sw)*8)];
#pragma unroll
        for (int nt = 0; nt < 2; ++nt) {
            const int rl = 15 - k_ + wn + nt*16 + lr;          // window-local row
            bf[nt] = *(const f16x8*)&lsW[rl*256 + (((qb + lh) ^ (rl & 31)) * 8)];
        }
#pragma unroll
        for (int mt = 0; mt < 2; ++mt)
#pragma unroll
            for (int nt = 0; nt < 2; ++nt)
                acc[mt][nt] = __builtin_amdgcn_mfma_f32_16x16x32_f16(
                    af[mt], bf[nt], acc[mt][nt], 0, 0, 0);
        __syncthreads();
    }
#undef ASTG
#pragma unroll
    for (int mt = 0; mt < 2; ++mt)
#pragma unroll
        for (int nt = 0; nt < 2; ++nt)
#pragma unroll
            for (int rg = 0; rg < 4; ++rg) {
                const int r = o0 + wo + mt*16 + lh*4 + rg;
                const int c = n0 + wn + nt*16 + lr;
                out[(long long)r*N_TOT + c] = tanhf(acc[mt][nt][rg]);
            }
}

extern "C" void kernel_launch(void* const* d_in, const int* in_sizes, int n_in,
                              void* d_out, int out_size, void* d_ws, size_t ws_size,
                              hipStream_t stream) {
    const float* u = (const float*)d_in[0];
    const float* A = (const float*)d_in[1];
    const float* B = (const float*)d_in[2];
    const float* C = (const float*)d_in[3];
    const float* D = (const float*)d_in[4];
    char* ws = (char*)d_ws;
    PTRS(ws)
    f16* Uh = (f16*)(ws + OFF_UH);
    float* out = (float*)d_out;

    prep_kernel<<<3330, 256, 0, stream>>>(u, A, B, C, ws);
    // S1: A2=(2A)^2 [256], T2=A2^T [256], P1=C(2A) [64]          -> 576 blocks
    stage64_kernel<<<576, 256, 0, stream>>>(As, T1, A2, 256,
                                            T1, As, T2, 512,
                                            Cc, T1, P1, 576,
                                            As, T1, A2 /*unreachable*/);
    // S2: A4 [256], T4=(A4)^T [256], P2=C A2 [64], P3=P1 A2 [64] -> 640 blocks
    stage64_kernel<<<640, 256, 0, stream>>>(A2, T2, A4, 256,
                                            T2, A2, T4, 512,
                                            Cc, T2, P2, 576,
                                            P1, T2, P3);
    // S3: A8=A4 A4 [256], QT4=(A4 B)^T = BhT @ A4^T [64]         -> 320 blocks
    stage64_kernel<<<320, 256, 0, stream>>>(A4, T4, A8, 256,
                                            BhT, A4, QT4, 320,
                                            As, T1, A2, 320,
                                            As, T1, A2 /*unreachable*/);
    // S4: QT8=(A8 B)^T [64], QT12=QT4 @ A8^T [64]                -> 128 blocks
    stage64_kernel<<<128, 256, 0, stream>>>(BhT, A8, QT8, 64,
                                            QT4, A8, QT12, 128,
                                            As, T1, A2, 128,
                                            As, T1, A2 /*unreachable*/);
    // S5: G_k (16 k-values x 16 tiles)
    g64_kernel<<<256, 256, 0, stream>>>(Cc, BhT, Gc, D);
    // conv-GEMM + tanh -> (256 x 16384) f32
    conv_kernel<<<dim3(N_TOT/64, 4), 256, 0, stream>>>(Gc, Uh, out);
}